// Round 6
// baseline (443.153 us; speedup 1.0000x reference)
//
#include <hip/hip_runtime.h>
#include <hip/hip_bf16.h>

#define TOK 4096
#define HD 1024
#define ID 512
#define NE 64
#define TK 8
#define CAP 1024
#define NROUTE 32768   // TOK*TK
#define NCHUNK 128     // NROUTE/256

typedef __attribute__((ext_vector_type(4))) float f32x4;
typedef __attribute__((ext_vector_type(8))) short s16x8;
typedef __attribute__((ext_vector_type(2))) __bf16 bf16x2;

__device__ __forceinline__ ushort f2bf(float f){
  uint u = __builtin_bit_cast(uint, f);
  u += 0x7fffu + ((u >> 16) & 1u);
  return (ushort)(u >> 16);
}
__device__ __forceinline__ float bf2f(ushort b){
  uint u = ((uint)b) << 16;
  return __builtin_bit_cast(float, u);
}
__device__ __forceinline__ uint2 f4_to_bf4(float4 v){
  bf16x2 p0; p0[0] = (__bf16)v.x; p0[1] = (__bf16)v.y;
  bf16x2 p1; p1[0] = (__bf16)v.z; p1[1] = (__bf16)v.w;
  uint2 r; r.x = __builtin_bit_cast(uint, p0); r.y = __builtin_bit_cast(uint, p1);
  return r;
}
__device__ __forceinline__ short bfs(float f){
  __bf16 h = (__bf16)f;
  return __builtin_bit_cast(short, h);
}
__device__ __forceinline__ s16x8 pack8(float4 a, float4 b){
  s16x8 r;
  r[0]=bfs(a.x); r[1]=bfs(a.y); r[2]=bfs(a.z); r[3]=bfs(a.w);
  r[4]=bfs(b.x); r[5]=bfs(b.y); r[6]=bfs(b.z); r[7]=bfs(b.w);
  return r;
}
__device__ __forceinline__ void gld16(void* lds, const void* g){
  __builtin_amdgcn_global_load_lds((const __attribute__((address_space(1))) unsigned int*)g,
                                   (__attribute__((address_space(3))) unsigned int*)lds, 16, 0, 0);
}

// ---------------- X -> bf16 pre-convert --------------------------------------
__global__ __launch_bounds__(256)
void cvtX_kernel(const float* __restrict__ X, ushort* __restrict__ Xbf){
  size_t i = ((size_t)blockIdx.x*256 + threadIdx.x) * 8;
  float4 a = *(const float4*)(X + i);
  float4 b = *(const float4*)(X + i + 4);
  uint2 lo = f4_to_bf4(a), hi = f4_to_bf4(b);
  uint4 o; o.x = lo.x; o.y = lo.y; o.z = hi.x; o.w = hi.y;
  *(uint4*)(Xbf + i) = o;
}

// ---------------- gating: fp64-accurate scores + top-8 + normalized weights --
__global__ __launch_bounds__(256)
void gating_kernel(const float* __restrict__ X, const float* __restrict__ GW,
                   int* __restrict__ topi, float* __restrict__ topw)
{
  __shared__ float xt[16][68];
  __shared__ float gt[64][68];
  __shared__ double ds[16][72];
  const int tid = threadIdx.x;
  const int tbase = blockIdx.x * 16;
  const int t = tid & 15, e0 = (tid >> 4) * 4;
  double acc[4] = {0.0, 0.0, 0.0, 0.0};
  for (int hc=0; hc<HD; hc+=64){
    { int r = tid >> 4, c4 = (tid & 15) * 4;
      *(float4*)&xt[r][c4] = *(const float4*)(X + (size_t)(tbase+r)*HD + hc + c4); }
    #pragma unroll
    for (int it=0; it<4; ++it){
      int idx = it*256 + tid;
      int r = idx >> 4, c4 = (idx & 15) * 4;
      *(float4*)&gt[r][c4] = *(const float4*)(GW + (size_t)r*HD + hc + c4);
    }
    __syncthreads();
    #pragma unroll
    for (int k4=0; k4<16; ++k4){
      float4 xv = *(const float4*)&xt[t][k4*4];
      #pragma unroll
      for (int j=0;j<4;++j){
        float4 gv = *(const float4*)&gt[e0+j][k4*4];
        acc[j] += (double)xv.x*(double)gv.x + (double)xv.y*(double)gv.y
                + (double)xv.z*(double)gv.z + (double)xv.w*(double)gv.w;
      }
    }
    __syncthreads();
  }
  #pragma unroll
  for (int j=0;j<4;++j) ds[t][e0+j] = acc[j];
  __syncthreads();
  if (tid < 16){
    int tt = tid;
    int idxs[8]; double vals[8]; double sum = 0.0;
    #pragma unroll
    for (int k=0;k<8;++k){
      double best = -1e300; int bi = 0;
      for (int e=0;e<NE;++e){ double v = ds[tt][e]; if (v > best){ best = v; bi = e; } }
      ds[tt][bi] = -1e300;
      double w = 1.0 / (1.0 + exp(-best));
      idxs[k] = bi; vals[k] = w; sum += w;
    }
    double inv = 1.0 / sum;
    #pragma unroll
    for (int k=0;k<8;++k){
      topi[(size_t)(tbase+tt)*TK + k] = idxs[k];
      topw[(size_t)(tbase+tt)*TK + k] = (float)(vals[k]*inv);
    }
  }
}

// ---------------- dispatch bookkeeping ---------------------------------------
__global__ __launch_bounds__(256)
void hist_kernel(const int* __restrict__ topi, int* __restrict__ ccnt){
  __shared__ int h[NE];
  const int tid = threadIdx.x;
  if (tid < NE) h[tid] = 0;
  __syncthreads();
  atomicAdd(&h[topi[blockIdx.x*256 + tid]], 1);
  __syncthreads();
  if (tid < NE) ccnt[blockIdx.x*NE + tid] = h[tid];
}

__global__ __launch_bounds__(64)
void scan_kernel(const int* __restrict__ ccnt, int* __restrict__ cbase,
                 int* __restrict__ cntC, int* __restrict__ ebase){
  const int e = threadIdx.x;
  int run = 0;
  for (int c=0;c<NCHUNK;++c){ cbase[c*NE+e] = run; run += ccnt[c*NE+e]; }
  cntC[e] = run < CAP ? run : CAP;
  __syncthreads();
  if (e == 0){
    int s = 0;
    for (int i=0;i<NE;++i){ ebase[i] = s; s += cntC[i]; }
    ebase[NE] = s;
  }
}

__global__ __launch_bounds__(64)
void assign_kernel(const int* __restrict__ topi, const int* __restrict__ cbase,
                   int* __restrict__ pos, int* __restrict__ rowlist){
  __shared__ int es[256];
  const int tid = threadIdx.x;
  const int c = blockIdx.x;
  for (int i=tid;i<256;i+=64) es[i] = topi[c*256+i];
  __syncthreads();
  const int e = tid;
  int cntr = cbase[c*NE+e];
  for (int j=0;j<256;++j){
    if (es[j] == e){
      int n = c*256+j;
      pos[n] = cntr;
      if (cntr < CAP) rowlist[e*CAP + cntr] = n;
      ++cntr;
    }
  }
}

// ---------------- grouped gate/up GEMM + fused SwiGLU (v4: 2-phase dbuf) -----
// Block 128 rows x 64 i-cols (g+u => 128 B-rows). 4 waves 2x2; wave = 64 rows
// x (32g+32u). Double-buffered LDS; next-tile loads issued BEFORE compute so
// HBM latency hides under MFMA. One barrier per K-step.
template<bool SHARED>
__global__ __launch_bounds__(256,2)
void gateup_kernel(const ushort* __restrict__ Xbf, const float* __restrict__ WG,
                   const float* __restrict__ WU, const int* __restrict__ rowlist,
                   const int* __restrict__ cntC, const int* __restrict__ ebase,
                   ushort* __restrict__ interm)
{
  int e, mt, nt, cnt, outbase;
  if (SHARED){
    nt = blockIdx.x & 7; mt = blockIdx.x >> 3; e = 0; cnt = TOK; outbase = mt*128;
  } else {
    int x = blockIdx.x & 7; int rem = blockIdx.x >> 3;
    nt = rem & 7; mt = (rem >> 3) & 7; e = ((rem >> 6) << 3) | x;  // e%8==bid%8 -> XCD locality
    cnt = cntC[e];
    if (mt*128 >= cnt) return;
    outbase = ebase[e] + mt*128;
  }
  const size_t wof = SHARED ? 0 : (size_t)e*ID*HD;
  const float* wg = WG + wof + (size_t)nt*64*HD;
  const float* wu = WU + wof + (size_t)nt*64*HD;

  __shared__ ushort aL[2][64*128];  // 2 x 16KB: 64 lines(=128 rows) x 16 gran
  __shared__ ushort bL[2][64*128];  // 2 x 16KB: 128 B-rows(g|u)
  __shared__ int tokb[128];

  const int tid = threadIdx.x;
  if (tid < 128){
    int tokv;
    if (SHARED) tokv = mt*128 + tid;
    else tokv = (mt*128 + tid < cnt) ? (rowlist[e*CAP + mt*128 + tid] >> 3) : 0;
    tokb[tid] = tokv;
  }
  __syncthreads();

  const int w = tid >> 6, l = tid & 63;
  const int wm = w >> 1, wn = w & 1;
  const int fr = l & 15, fko = (l >> 4) * 8;

  // A staging: 4 gld16 rounds, inverse-swizzled global src, linear LDS dst
  uint aOff[4];
  #pragma unroll
  for (int j=0;j<4;++j){
    int f = j*256 + tid;
    int L = f >> 4, s = f & 15;
    int g = s ^ (L & 15);
    int r = 2*L + (g >> 3);
    aOff[j] = (uint)tokb[r]*HD + (uint)((g & 7)*8);
  }
  // B staging: 4 granules/thread (reg->cvt->swizzled ds_write)
  const float* bSrc[4]; int bDst[4];
  #pragma unroll
  for (int i=0;i<4;++i){
    int f = i*256 + tid;
    int L = f >> 4, s = f & 15;
    int g = s ^ (L & 15);
    int R = 2*L + (g >> 3);
    int gk = g & 7;
    bSrc[i] = ((R < 64) ? (wg + (size_t)R*HD) : (wu + (size_t)(R-64)*HD)) + gk*8;
    bDst[i] = f*8;
  }

  f32x4 acc[4][2][2];
  #pragma unroll
  for (int m=0;m<4;++m)
    #pragma unroll
    for (int a2=0;a2<2;++a2)
      #pragma unroll
      for (int c=0;c<2;++c) acc[m][a2][c] = (f32x4)0.0f;

  float4 br[4][2];

  auto loadB = [&](int kc){
    #pragma unroll
    for (int i=0;i<4;++i){
      br[i][0] = *(const float4*)(bSrc[i] + kc);
      br[i][1] = *(const float4*)(bSrc[i] + kc + 4);
    }
  };
  auto writeB = [&](int b){
    #pragma unroll
    for (int i=0;i<4;++i) *(s16x8*)&bL[b][bDst[i]] = pack8(br[i][0], br[i][1]);
  };
  auto stageA = [&](int b, int kc){
    #pragma unroll
    for (int j=0;j<4;++j) gld16(&aL[b][(j*256 + w*64)*8], Xbf + aOff[j] + kc);
  };

  // prologue: tile 0 fully staged
  loadB(0); stageA(0, 0); writeB(0);
  __syncthreads();

  for (int t=0; t<16; ++t){
    const int cur = t & 1, nxt = cur ^ 1;
    const int kc = t*64;
    if (t < 15){ loadB(kc + 64); stageA(nxt, kc + 64); }  // prefetch BEFORE compute
    // compute on buf[cur]
    s16x8 bfr[2][2][2];
    #pragma unroll
    for (int mat=0;mat<2;++mat)
      #pragma unroll
      for (int cg=0;cg<2;++cg)
        #pragma unroll
        for (int ks=0;ks<2;++ks){
          int R = mat*64 + wn*32 + cg*16 + fr;
          int gk = ks*4 + (fko>>3);
          int g = ((R&1)<<3) | gk;
          int L = R>>1;
          int gs = g ^ (L & 15);
          bfr[mat][cg][ks] = *(const s16x8*)&bL[cur][L*128 + gs*8];
        }
    #pragma unroll
    for (int mb=0;mb<4;++mb){
      #pragma unroll
      for (int ks=0;ks<2;++ks){
        int r = wm*64 + mb*16 + fr;
        int gk = ks*4 + (fko>>3);
        int g = ((r&1)<<3) | gk;
        int L = r>>1;
        int gs = g ^ (L & 15);
        s16x8 a = *(const s16x8*)&aL[cur][L*128 + gs*8];
        #pragma unroll
        for (int mat=0;mat<2;++mat)
          #pragma unroll
          for (int cg=0;cg<2;++cg)
            acc[mb][mat][cg] = __builtin_amdgcn_mfma_f32_16x16x32_bf16(a, bfr[mat][cg][ks], acc[mb][mat][cg], 0, 0, 0);
      }
    }
    if (t < 15) writeB(nxt);   // compiler waits vmcnt for br only
    __syncthreads();           // drains A gld16 (latency hidden under MFMA)
  }

  const int rq = (l >> 4) * 4;
  #pragma unroll
  for (int mb=0;mb<4;++mb){
    #pragma unroll
    for (int q=0;q<4;++q){
      int rloc = wm*64 + mb*16 + rq + q;
      if (!SHARED && mt*128 + rloc >= cnt) continue;
      size_t orow = (size_t)(outbase + rloc);
      #pragma unroll
      for (int cg=0;cg<2;++cg){
        float g = acc[mb][0][cg][q], u = acc[mb][1][cg][q];
        float sv = g / (1.0f + __expf(-g)) * u;   // silu(g)*u
        interm[orow*ID + (size_t)(nt*64 + wn*32 + cg*16 + fr)] = f2bf(sv);
      }
    }
  }
}

// ---------------- grouped down GEMM (v4: 2-phase dbuf) -----------------------
// Block 128 rows x 128 out-cols. 4 waves 2x2; wave = 64 rows x 64 cols. K=512.
template<bool SHARED>
__global__ __launch_bounds__(256,2)
void down_kernel(const ushort* __restrict__ interm, const float* __restrict__ WD,
                 const int* __restrict__ cntC, const int* __restrict__ ebase,
                 ushort* __restrict__ out_rows, float* __restrict__ outf)
{
  int e, mt, nt, cnt, abase;
  if (SHARED){
    nt = blockIdx.x & 7; mt = blockIdx.x >> 3; e = 0; cnt = TOK; abase = mt*128;
  } else {
    int x = blockIdx.x & 7; int rem = blockIdx.x >> 3;
    nt = rem & 7; mt = (rem >> 3) & 7; e = ((rem >> 6) << 3) | x;
    cnt = cntC[e];
    if (mt*128 >= cnt) return;
    abase = ebase[e] + mt*128;
  }
  const ushort* A = interm + (size_t)abase*ID;
  const float* wd = WD + (SHARED ? (size_t)0 : (size_t)e*HD*ID) + (size_t)nt*128*ID;

  __shared__ ushort aL[2][64*128];
  __shared__ ushort bL[2][64*128];

  const int tid = threadIdx.x;
  const int w = tid >> 6, l = tid & 63;
  const int wm = w >> 1, wn = w & 1;
  const int fr = l & 15, fko = (l >> 4) * 8;

  uint aOff[4];
  #pragma unroll
  for (int j=0;j<4;++j){
    int f = j*256 + tid;
    int L = f >> 4, s = f & 15;
    int g = s ^ (L & 15);
    int r = 2*L + (g >> 3);
    aOff[j] = (uint)r*ID + (uint)((g & 7)*8);
  }
  const float* bSrc[4]; int bDst[4];
  #pragma unroll
  for (int i=0;i<4;++i){
    int f = i*256 + tid;
    int L = f >> 4, s = f & 15;
    int g = s ^ (L & 15);
    int R = 2*L + (g >> 3);
    int gk = g & 7;
    bSrc[i] = wd + (size_t)R*ID + gk*8;
    bDst[i] = f*8;
  }

  f32x4 acc[4][4];
  #pragma unroll
  for (int m=0;m<4;++m)
    #pragma unroll
    for (int c=0;c<4;++c) acc[m][c] = (f32x4)0.0f;

  float4 br[4][2];

  auto loadB = [&](int kc){
    #pragma unroll
    for (int i=0;i<4;++i){
      br[i][0] = *(const float4*)(bSrc[i] + kc);
      br[i][1] = *(const float4*)(bSrc[i] + kc + 4);
    }
  };
  auto writeB = [&](int b){
    #pragma unroll
    for (int i=0;i<4;++i) *(s16x8*)&bL[b][bDst[i]] = pack8(br[i][0], br[i][1]);
  };
  auto stageA = [&](int b, int kc){
    #pragma unroll
    for (int j=0;j<4;++j) gld16(&aL[b][(j*256 + w*64)*8], A + aOff[j] + kc);
  };

  loadB(0); stageA(0, 0); writeB(0);
  __syncthreads();

  for (int t=0; t<8; ++t){
    const int cur = t & 1, nxt = cur ^ 1;
    const int kc = t*64;
    if (t < 7){ loadB(kc + 64); stageA(nxt, kc + 64); }
    s16x8 bfr[4][2];
    #pragma unroll
    for (int cg=0;cg<4;++cg)
      #pragma unroll
      for (int ks=0;ks<2;++ks){
        int R = wn*64 + cg*16 + fr;
        int gk = ks*4 + (fko>>3);
        int g = ((R&1)<<3) | gk;
        int L = R>>1;
        int gs = g ^ (L & 15);
        bfr[cg][ks] = *(const s16x8*)&bL[cur][L*128 + gs*8];
      }
    #pragma unroll
    for (int mb=0;mb<4;++mb){
      #pragma unroll
      for (int ks=0;ks<2;++ks){
        int r = wm*64 + mb*16 + fr;
        int gk = ks*4 + (fko>>3);
        int g = ((r&1)<<3) | gk;
        int L = r>>1;
        int gs = g ^ (L & 15);
        s16x8 a = *(const s16x8*)&aL[cur][L*128 + gs*8];
        #pragma unroll
        for (int cg=0;cg<4;++cg)
          acc[mb][cg] = __builtin_amdgcn_mfma_f32_16x16x32_bf16(a, bfr[cg][ks], acc[mb][cg], 0, 0, 0);
      }
    }
    if (t < 7) writeB(nxt);
    __syncthreads();
  }

  const int rq = (l >> 4) * 4;
  #pragma unroll
  for (int mb=0;mb<4;++mb){
    #pragma unroll
    for (int q=0;q<4;++q){
      int rloc = wm*64 + mb*16 + rq + q;
      if (!SHARED && mt*128 + rloc >= cnt) continue;
      #pragma unroll
      for (int cg=0;cg<4;++cg){
        float v = acc[mb][cg][q];
        int colg = nt*128 + wn*64 + cg*16 + fr;
        if (SHARED) outf[(size_t)(mt*128 + rloc)*HD + colg] = v;
        else        out_rows[(size_t)(abase + rloc)*HD + colg] = f2bf(v);
      }
    }
  }
}

// ---------------- combine: out += sum_k topw * routed_row --------------------
__global__ __launch_bounds__(256)
void combine_kernel(const int* __restrict__ topi, const float* __restrict__ topw,
                    const int* __restrict__ pos, const int* __restrict__ ebase,
                    const ushort* __restrict__ out_rows, float* __restrict__ out)
{
  const int t = blockIdx.x;
  const int tid = threadIdx.x;
  __shared__ int rws[TK];
  __shared__ float wts[TK];
  if (tid < TK){
    int e = topi[(size_t)t*TK + tid];
    int p = pos[(size_t)t*TK + tid];
    rws[tid] = (p < CAP) ? (ebase[e] + p) : -1;
    wts[tid] = topw[(size_t)t*TK + tid];
  }
  __syncthreads();
  const int h0 = tid * 4;
  float4 acc = *(float4*)(out + (size_t)t*HD + h0);
  #pragma unroll
  for (int k=0;k<TK;++k){
    int r = rws[k];
    if (r < 0) continue;
    ushort4 v = *(const ushort4*)(out_rows + (size_t)r*HD + h0);
    float wk = wts[k];
    acc.x += wk*bf2f(v.x); acc.y += wk*bf2f(v.y);
    acc.z += wk*bf2f(v.z); acc.w += wk*bf2f(v.w);
  }
  *(float4*)(out + (size_t)t*HD + h0) = acc;
}

// ---------------- launch ------------------------------------------------------
extern "C" void kernel_launch(void* const* d_in, const int* in_sizes, int n_in,
                              void* d_out, int out_size, void* d_ws, size_t ws_size,
                              hipStream_t stream)
{
  (void)in_sizes; (void)n_in; (void)out_size; (void)ws_size;
  const float* X   = (const float*)d_in[0];
  const float* GW  = (const float*)d_in[1];
  const float* SWG = (const float*)d_in[2];
  const float* SWU = (const float*)d_in[3];
  const float* SWD = (const float*)d_in[4];
  const float* EWG = (const float*)d_in[5];
  const float* EWU = (const float*)d_in[6];
  const float* EWD = (const float*)d_in[7];
  float* OUT = (float*)d_out;

  char* p = (char*)d_ws;
  int*    topi    = (int*)p;      p += (size_t)NROUTE*4;
  float*  topw    = (float*)p;    p += (size_t)NROUTE*4;
  int*    pos     = (int*)p;      p += (size_t)NROUTE*4;
  int*    ccnt    = (int*)p;      p += (size_t)NCHUNK*NE*4;
  int*    cbase   = (int*)p;      p += (size_t)NCHUNK*NE*4;
  int*    cntC    = (int*)p;      p += 256;
  int*    ebase   = (int*)p;      p += 512;
  int*    rowlist = (int*)p;      p += (size_t)NE*CAP*4;
  ushort* Xbf     = (ushort*)p;   p += (size_t)TOK*HD*2;
  ushort* interm_r= (ushort*)p;   p += (size_t)(NROUTE+256)*ID*2;
  ushort* interm_s= (ushort*)p;   p += (size_t)TOK*ID*2;
  ushort* out_rows= (ushort*)p;   p += (size_t)NROUTE*HD*2;

  cvtX_kernel<<<TOK*HD/8/256, 256, 0, stream>>>(X, Xbf);
  gating_kernel<<<256, 256, 0, stream>>>(X, GW, topi, topw);
  hist_kernel<<<NCHUNK, 256, 0, stream>>>(topi, ccnt);
  scan_kernel<<<1, 64, 0, stream>>>(ccnt, cbase, cntC, ebase);
  assign_kernel<<<NCHUNK, 64, 0, stream>>>(topi, cbase, pos, rowlist);

  gateup_kernel<false><<<4096, 256, 0, stream>>>(Xbf, EWG, EWU, rowlist, cntC, ebase, interm_r);
  gateup_kernel<true ><<<256,  256, 0, stream>>>(Xbf, SWG, SWU, nullptr, nullptr, nullptr, interm_s);
  down_kernel<false><<<4096, 256, 0, stream>>>(interm_r, EWD, cntC, ebase, out_rows, nullptr);
  down_kernel<true ><<<256,  256, 0, stream>>>(interm_s, SWD, nullptr, nullptr, nullptr, OUT);

  combine_kernel<<<TOK, 256, 0, stream>>>(topi, topw, pos, ebase, out_rows, OUT);
}